// Round 1
// 339.669 us; speedup vs baseline: 1.0037x; 1.0037x over previous
//
#include <hip/hip_runtime.h>
#include <math.h>

#define BATCH 16384
#define KN 32       // neighbors
#define DF 128      // feature dim
#define NM 4        // masks
#define RPB 4       // batch rows per block (one wave64 per row)

// Block = 256 threads = 4 waves; each wave owns one batch row.
// Lane l of a wave: h = l>>5 selects k-half (0: k=0..15, 1: k=16..31),
// f = l&31 selects the float4 chunk of the 128-float feature row.
// Each lane accumulates 16 neighbors (16 independent coalesced float4
// gathers), then one __shfl_xor(32) pass combines the two halves.
// vs previous version: half the per-thread serial load chain, ~2/3 the
// register pressure, 1.5x the target occupancy (24 vs 16 waves/CU).
__global__ __launch_bounds__(256, 6) void wagg_kernel(
    const float* __restrict__ embed,
    const int*   __restrict__ nidx,
    const float* __restrict__ nw,
    float*       __restrict__ out)
{
    const int t  = threadIdx.x;
    const int wv = t >> 6;   // wave within block = row within block
    const int l  = t & 63;   // lane
    const int h  = l >> 5;   // k-half
    const int f  = l & 31;   // float4 chunk
    const int b  = blockIdx.x * RPB + wv;

    __shared__ int   sidx[RPB][KN];
    __shared__ float sw  [RPB][KN];   // w
    __shared__ float ssq [RPB][KN];   // sqrt(w)

    // ---- staging: both halves load k=f (identical values), h==0 writes LDS ----
    const float w  = nw[(size_t)b * KN + f];
    const float sq = sqrtf(w);
    if (h == 0) {
        sidx[wv][f] = nidx[(size_t)b * KN + f];
        sw  [wv][f] = w;
        ssq [wv][f] = sq;
    }

    // butterfly sums over the 32 k's (each 32-lane half holds one full copy,
    // so xor masks 1..16 stay within the half and both halves get the sums).
    // mask 0 sum == 32 exactly -> constant, not computed.
    float s1 = sq;          // sum sqrt(w)
    float s2 = w;           // sum w
    float s3 = w * sq;      // sum w^1.5
    #pragma unroll
    for (int m = 1; m < 32; m <<= 1) {
        s1 += __shfl_xor(s1, m);
        s2 += __shfl_xor(s2, m);
        s3 += __shfl_xor(s3, m);
    }

    __syncthreads();

    // ---- gather + weighted accumulate: 16 independent loads per lane ----
    float4 a0, a1, a2, a3;
    a0.x=a0.y=a0.z=a0.w=0.f;
    a1.x=a1.y=a1.z=a1.w=0.f;
    a2.x=a2.y=a2.z=a2.w=0.f;
    a3.x=a3.y=a3.z=a3.w=0.f;

    const int kb = h << 4;
    #pragma unroll
    for (int k = 0; k < 16; ++k) {
        const int   row = sidx[wv][kb + k];   // LDS broadcast
        const float wk  = sw [wv][kb + k];
        const float sk  = ssq[wv][kb + k];
        const float wsk = wk * sk;
        const float4 v  = *((const float4*)(embed + (size_t)row * DF) + f);
        a0.x += v.x;        a0.y += v.y;        a0.z += v.z;        a0.w += v.w;
        a1.x += sk  * v.x;  a1.y += sk  * v.y;  a1.z += sk  * v.z;  a1.w += sk  * v.w;
        a2.x += wk  * v.x;  a2.y += wk  * v.y;  a2.z += wk  * v.z;  a2.w += wk  * v.w;
        a3.x += wsk * v.x;  a3.y += wsk * v.y;  a3.z += wsk * v.z;  a3.w += wsk * v.w;
    }

    // ---- cross-half combine: lane (h,f) + lane (h^1,f) ----
    a0.x += __shfl_xor(a0.x, 32); a0.y += __shfl_xor(a0.y, 32);
    a0.z += __shfl_xor(a0.z, 32); a0.w += __shfl_xor(a0.w, 32);
    a1.x += __shfl_xor(a1.x, 32); a1.y += __shfl_xor(a1.y, 32);
    a1.z += __shfl_xor(a1.z, 32); a1.w += __shfl_xor(a1.w, 32);
    a2.x += __shfl_xor(a2.x, 32); a2.y += __shfl_xor(a2.y, 32);
    a2.z += __shfl_xor(a2.z, 32); a2.w += __shfl_xor(a2.w, 32);
    a3.x += __shfl_xor(a3.x, 32); a3.y += __shfl_xor(a3.y, 32);
    a3.z += __shfl_xor(a3.z, 32); a3.w += __shfl_xor(a3.w, 32);

    // ---- normalize + write: half h writes masks 2h and 2h+1 ----
    const float i0 = 1.0f / 32.0f;
    const float i1 = 1.0f / s1;
    const float i2 = 1.0f / s2;
    const float i3 = 1.0f / s3;

    float4 u0, u1;
    float  c0, c1;
    if (h == 0) { u0 = a0; c0 = i0; u1 = a1; c1 = i1; }
    else        { u0 = a2; c0 = i2; u1 = a3; c1 = i3; }
    u0.x *= c0; u0.y *= c0; u0.z *= c0; u0.w *= c0;
    u1.x *= c1; u1.y *= c1; u1.z *= c1; u1.w *= c1;

    float4* o = (float4*)(out + (size_t)b * (NM * DF));
    o[(2 * h)     * 32 + f] = u0;   // mask 2h,   chunk f (coalesced 512B/half)
    o[(2 * h + 1) * 32 + f] = u1;   // mask 2h+1, chunk f
}

extern "C" void kernel_launch(void* const* d_in, const int* in_sizes, int n_in,
                              void* d_out, int out_size, void* d_ws, size_t ws_size,
                              hipStream_t stream) {
    const float* embed = (const float*)d_in[0];   // [500000, 128] f32
    const int*   nidx  = (const int*)  d_in[1];   // [16384, 32] i32
    const float* nw    = (const float*)d_in[2];   // [16384, 32] f32
    float* out = (float*)d_out;                   // [16384, 512] f32

    wagg_kernel<<<BATCH / RPB, 256, 0, stream>>>(embed, nidx, nw, out);
}